// Round 6
// baseline (86.874 us; speedup 1.0000x reference)
//
#include <hip/hip_runtime.h>
#include <hip/hip_bf16.h>
#include <math.h>

typedef _Float16 half8_t __attribute__((ext_vector_type(8)));
typedef _Float16 half4_t __attribute__((ext_vector_type(4)));
typedef float floatx4 __attribute__((ext_vector_type(4)));

#define TILES 4   // row-tiles of 64 per block; grid = B/(64*TILES) = 512 (2/CU)

// ---------------------------------------------------------------------------
// K0: repack fp32 weights (K x N row-major) into fp16 MFMA B-fragment layout:
// dst[((nt*KS+ks)*64 + lane)*8 + j] = (half) W[ks*32 + (lane>>4)*8 + j][nt*16 + (lane&15)]
// zero-padded for k >= K or col >= N.  One merged launch for W1/W2/W3.
// ---------------------------------------------------------------------------
__device__ __forceinline__ void prep_body(const float* __restrict__ W,
                                          _Float16* __restrict__ dst,
                                          int K, int N, int KS, int b) {
    int ks   = b % KS;
    int nt   = b / KS;
    int lane = threadIdx.x;         // 64
    int col  = nt * 16 + (lane & 15);
    int kbase = ks * 32 + ((lane >> 4) << 3);
    half8_t v;
#pragma unroll
    for (int j = 0; j < 8; ++j) {
        int k = kbase + j;
        float x = (k < K && col < N) ? W[(size_t)k * N + col] : 0.f;
        v[j] = (_Float16)x;
    }
    *(half8_t*)(dst + (size_t)(b * 64 + lane) * 8) = v;
}

__global__ void prep_all(const float* __restrict__ W1, const float* __restrict__ W2,
                         const float* __restrict__ W3,
                         _Float16* __restrict__ w1f, _Float16* __restrict__ w2f,
                         _Float16* __restrict__ w3f) {
    int b = blockIdx.x;
    if (b < 64)      prep_body(W1, w1f, 252, 128, 8, b);
    else if (b < 80) prep_body(W2, w2f, 128, 64, 4, b - 64);
    else             prep_body(W3, w3f, 64, 5, 2, b - 80);
}

// ---------------------------------------------------------------------------
// K1: front MLP, N-split across waves, B register-resident, 4-tile loop with
// register prefetch of the next A-tile (16 x fp32x4 per lane) so every wave
// keeps ~16KB of HBM requests in flight during its whole compute phase.
//   LDS 56KB: sA [64][512B] @0, h1 [64][256B] @32768, h2 [64][128B] @49152.
//   Barriers per tile: post-stage, post-h1, post-h2 (h1 has its own region so
//   no barrier between GEMM1-reads-sA and h1-writes).
// ---------------------------------------------------------------------------
__global__ __launch_bounds__(256, 2) void front_kernel(
    const float* __restrict__ state,
    const _Float16* __restrict__ w1f, const float* __restrict__ b1,
    const _Float16* __restrict__ w2f, const float* __restrict__ b2,
    const _Float16* __restrict__ w3f, const float* __restrict__ b3,
    float* __restrict__ enc) {
    __shared__ char lds[57344];
    const int tid = threadIdx.x;
    const int w   = tid >> 6;
    const int l   = tid & 63;
    const int l15 = l & 15;
    const int lhi = l >> 4;
    const int wrow = w * 16;
    const int row0 = blockIdx.x * (64 * TILES);

    // staging geometry: lane -> (srow = wrow + l>>2, chunk = l&3);
    // iteration i covers float cols i*16 + chunk*4 .. +3 (16B, coalesced 64B/4 lanes)
    const int srow = wrow + (l >> 2);
    const int sc   = (l & 3) * 4;
    const int swz  = (srow & 7) << 4;

    // ---- B-fragment preload (L2-resident), held in VGPRs to the end ----
    half8_t bw1[2][8], bw2[4], bw3[2];
#pragma unroll
    for (int ntl = 0; ntl < 2; ++ntl)
#pragma unroll
        for (int ks = 0; ks < 8; ++ks)
            bw1[ntl][ks] = *(const half8_t*)(w1f + (size_t)(((w * 2 + ntl) * 8 + ks) * 64 + l) * 8);
#pragma unroll
    for (int ks = 0; ks < 4; ++ks)
        bw2[ks] = *(const half8_t*)(w2f + (size_t)((w * 4 + ks) * 64 + l) * 8);
#pragma unroll
    for (int ks = 0; ks < 2; ++ks)
        bw3[ks] = *(const half8_t*)(w3f + (size_t)(ks * 64 + l) * 8);

    floatx4 pf[16];                       // prefetched A chunks (64 VGPR)

#define ISSUE_A(TILE)                                                           \
    {                                                                           \
        const float* Arow = state + (size_t)(row0 + (TILE) * 64 + srow) * 252;  \
        _Pragma("unroll")                                                       \
        for (int i = 0; i < 16; ++i) {                                          \
            int cf = i * 16 + sc;                                               \
            if (cf < 252) pf[i] = *(const floatx4*)(Arow + cf);                 \
        }                                                                       \
    }

    ISSUE_A(0)

#pragma unroll
    for (int t = 0; t < TILES; ++t) {
        // ---- stage: convert pf -> sA (swizzled fp16) ----
#pragma unroll
        for (int i = 0; i < 16; ++i) {
            int cf = i * 16 + sc;
            half4_t h;
            if (cf < 252) {
                floatx4 f = pf[i];
                h = half4_t{ (_Float16)f[0], (_Float16)f[1], (_Float16)f[2], (_Float16)f[3] };
            } else {
                h = half4_t{ 0, 0, 0, 0 };   // K-pad 252..255
            }
            *(half4_t*)(lds + (srow << 9) + ((cf * 2) ^ swz)) = h;
        }
        __syncthreads();                  // sA complete (vmcnt already drained)

        // ---- issue next tile's loads NOW: in flight across all of GEMM1+ ----
        if (t + 1 < TILES) ISSUE_A(t + 1)

        // ---- GEMM1: [64 x 256] @ [256 x 32(cols w*32..)] ----
        floatx4 acc1[4][2];
#pragma unroll
        for (int mi = 0; mi < 4; ++mi)
#pragma unroll
            for (int ntl = 0; ntl < 2; ++ntl) acc1[mi][ntl] = floatx4{0, 0, 0, 0};

#pragma unroll
        for (int ks = 0; ks < 8; ++ks) {
            half8_t a[4];
#pragma unroll
            for (int mi = 0; mi < 4; ++mi) {
                int r = mi * 16 + l15;
                int cb = ks * 64 + lhi * 16;
                a[mi] = *(const half8_t*)(lds + (r << 9) + (cb ^ ((r & 7) << 4)));
            }
#pragma unroll
            for (int mi = 0; mi < 4; ++mi)
#pragma unroll
                for (int ntl = 0; ntl < 2; ++ntl)
                    acc1[mi][ntl] = __builtin_amdgcn_mfma_f32_16x16x32_f16(a[mi], bw1[ntl][ks], acc1[mi][ntl], 0, 0, 0);
        }

        // ---- h1 = relu(acc1 + b1) -> LDS @32768 (own region, no barrier) ----
#pragma unroll
        for (int ntl = 0; ntl < 2; ++ntl) {
            int col = (w * 2 + ntl) * 16 + l15;
            float bb = b1[col];
#pragma unroll
            for (int mi = 0; mi < 4; ++mi)
#pragma unroll
                for (int ri = 0; ri < 4; ++ri) {
                    int row = mi * 16 + lhi * 4 + ri;
                    float v = acc1[mi][ntl][ri] + bb;
                    v = v > 0.f ? v : 0.f;
                    *(_Float16*)(lds + 32768 + (row << 8) + ((col * 2) ^ ((row & 7) << 4))) = (_Float16)v;
                }
        }
        __syncthreads();                  // h1 complete

        // ---- GEMM2: [64 x 128] @ [128 x 16(cols w*16..)] ----
        floatx4 acc2[4];
#pragma unroll
        for (int mi = 0; mi < 4; ++mi) acc2[mi] = floatx4{0, 0, 0, 0};
#pragma unroll
        for (int ks = 0; ks < 4; ++ks)
#pragma unroll
            for (int mi = 0; mi < 4; ++mi) {
                int r = mi * 16 + l15;
                int cb = ks * 64 + lhi * 16;
                half8_t a = *(const half8_t*)(lds + 32768 + (r << 8) + (cb ^ ((r & 7) << 4)));
                acc2[mi] = __builtin_amdgcn_mfma_f32_16x16x32_f16(a, bw2[ks], acc2[mi], 0, 0, 0);
            }

        // ---- h2 = relu(acc2 + b2) -> LDS @49152 (own region) ----
        {
            int col = w * 16 + l15;
            float bb = b2[col];
#pragma unroll
            for (int mi = 0; mi < 4; ++mi)
#pragma unroll
                for (int ri = 0; ri < 4; ++ri) {
                    int row = mi * 16 + lhi * 4 + ri;
                    float v = acc2[mi][ri] + bb;
                    v = v > 0.f ? v : 0.f;
                    *(_Float16*)(lds + 49152 + (row << 7) + ((col * 2) ^ ((row & 7) << 4))) = (_Float16)v;
                }
        }
        __syncthreads();                  // h2 complete

        // ---- GEMM3: rows w*16..+15, [16 x 64] @ [64 x 16] (cols 0..4) ----
        floatx4 acc3 = floatx4{0, 0, 0, 0};
#pragma unroll
        for (int ks = 0; ks < 2; ++ks) {
            int r = wrow + l15;
            int cb = ks * 64 + lhi * 16;
            half8_t a = *(const half8_t*)(lds + 49152 + (r << 7) + (cb ^ ((r & 7) << 4)));
            acc3 = __builtin_amdgcn_mfma_f32_16x16x32_f16(a, bw3[ks], acc3, 0, 0, 0);
        }

        // ---- enc = tanh(acc3 + b3), cols 0..4 ----
        if (l15 < 5) {
            float bb = b3[l15];
#pragma unroll
            for (int ri = 0; ri < 4; ++ri) {
                int row = row0 + t * 64 + wrow + lhi * 4 + ri;
                enc[(size_t)row * 5 + l15] = tanhf(acc3[ri] + bb);
            }
        }
        // loop-around: next stage writes sA (last read in GEMM1, ordered by the
        // two barriers above); h2 last read here, ordered by next post-stage bar.
    }
#undef ISSUE_A
}

// ---------------------------------------------------------------------------
// K2: quantum circuit + back MLP, one thread per batch row.
// wire w <-> bit (4-w) of the flat amplitude index (wire 0 = MSB).
// ---------------------------------------------------------------------------
template<int P>
__device__ __forceinline__ void ry_g(float* re, float* im, float c, float s) {
    constexpr int STR = 1 << P;
#pragma unroll
    for (int base = 0; base < 32; base += 2 * STR)
#pragma unroll
        for (int d = 0; d < STR; ++d) {
            int i0 = base + d, i1 = i0 + STR;
            float r0 = re[i0], r1 = re[i1], m0 = im[i0], m1 = im[i1];
            re[i0] = c * r0 - s * r1;  re[i1] = s * r0 + c * r1;
            im[i0] = c * m0 - s * m1;  im[i1] = s * m0 + c * m1;
        }
}

template<int P>
__device__ __forceinline__ void rz_g(float* re, float* im, float c, float s) {
#pragma unroll
    for (int i = 0; i < 32; ++i) {
        float t = ((i >> P) & 1) ? s : -s;    // bit0: e^{-i h}, bit1: e^{+i h}
        float r = re[i], m = im[i];
        re[i] = c * r - t * m;
        im[i] = c * m + t * r;
    }
}

template<int PC, int PT>
__device__ __forceinline__ void cnot_g(float* re, float* im) {
#pragma unroll
    for (int i = 0; i < 32; ++i) {
        if (((i >> PC) & 1) && !((i >> PT) & 1)) {
            int j = i | (1 << PT);
            float t;
            t = re[i]; re[i] = re[j]; re[j] = t;
            t = im[i]; im[i] = im[j]; im[j] = t;
        }
    }
}

__global__ __launch_bounds__(256) void back_kernel(
    const float* __restrict__ enc, const float* __restrict__ qp,
    const float* __restrict__ D1, const float* __restrict__ d1,
    const float* __restrict__ D2, const float* __restrict__ d2,
    const float* __restrict__ D3, const float* __restrict__ d3,
    float* __restrict__ out) {
    __shared__ float sD1[160], sd1[32], sD2[512], sd2[16], sD3[64], sd3[4];
    __shared__ float sQc[30], sQs[30];
    const int tid = threadIdx.x;
    for (int i = tid; i < 512; i += 256) sD2[i] = D2[i];
    if (tid < 160) sD1[tid] = D1[tid];
    if (tid < 32)  sd1[tid] = d1[tid];
    if (tid < 64)  sD3[tid] = D3[tid];
    if (tid < 16)  sd2[tid] = d2[tid];
    if (tid < 4)   sd3[tid] = d3[tid];
    if (tid < 30) { float h = 0.5f * qp[tid]; sQc[tid] = cosf(h); sQs[tid] = sinf(h); }
    __syncthreads();

    const size_t r = (size_t)blockIdx.x * 256 + tid;

    // encoding: product state from RY(enc_i * pi) on |0...0>
    float cq[5], sq[5];
    const float HPI = 1.57079632679489662f;   // pi/2
#pragma unroll
    for (int i = 0; i < 5; ++i) {
        float a = enc[r * 5 + i] * HPI;
        cq[i] = cosf(a);
        sq[i] = sinf(a);
    }
    float re[32], im[32];
#pragma unroll
    for (int i = 0; i < 32; ++i) {
        float v = ((i >> 4) & 1) ? sq[0] : cq[0];
        v *= ((i >> 3) & 1) ? sq[1] : cq[1];
        v *= ((i >> 2) & 1) ? sq[2] : cq[2];
        v *= ((i >> 1) & 1) ? sq[3] : cq[3];
        v *= ( i       & 1) ? sq[4] : cq[4];
        re[i] = v;
        im[i] = 0.f;
    }

#pragma unroll
    for (int lay = 0; lay < 3; ++lay) {
        const float* c = sQc + lay * 10;
        const float* s = sQs + lay * 10;
        ry_g<4>(re, im, c[0], s[0]);  rz_g<4>(re, im, c[1], s[1]);
        ry_g<3>(re, im, c[2], s[2]);  rz_g<3>(re, im, c[3], s[3]);
        ry_g<2>(re, im, c[4], s[4]);  rz_g<2>(re, im, c[5], s[5]);
        ry_g<1>(re, im, c[6], s[6]);  rz_g<1>(re, im, c[7], s[7]);
        ry_g<0>(re, im, c[8], s[8]);  rz_g<0>(re, im, c[9], s[9]);
        cnot_g<4, 3>(re, im);
        cnot_g<3, 2>(re, im);
        cnot_g<2, 1>(re, im);
        cnot_g<1, 0>(re, im);
    }

    float q[5] = {0, 0, 0, 0, 0};
#pragma unroll
    for (int i = 0; i < 32; ++i) {
        float p = re[i] * re[i] + im[i] * im[i];
        q[0] += ((i >> 4) & 1) ? -p : p;
        q[1] += ((i >> 3) & 1) ? -p : p;
        q[2] += ((i >> 2) & 1) ? -p : p;
        q[3] += ((i >> 1) & 1) ? -p : p;
        q[4] += ( i       & 1) ? -p : p;
    }

    // back MLP: q(5) -> 32 relu -> 16 relu -> 4
    float h1[32];
#pragma unroll
    for (int j = 0; j < 32; ++j) {
        float a = sd1[j];
#pragma unroll
        for (int k = 0; k < 5; ++k) a += q[k] * sD1[k * 32 + j];
        h1[j] = a > 0.f ? a : 0.f;
    }
    float h2[16];
#pragma unroll
    for (int j = 0; j < 16; ++j) {
        float a = sd2[j];
#pragma unroll
        for (int k = 0; k < 32; ++k) a += h1[k] * sD2[k * 16 + j];
        h2[j] = a > 0.f ? a : 0.f;
    }
    floatx4 o;
#pragma unroll
    for (int j = 0; j < 4; ++j) {
        float a = sd3[j];
#pragma unroll
        for (int k = 0; k < 16; ++k) a += h2[k] * sD3[k * 4 + j];
        o[j] = a;
    }
    *(floatx4*)(out + r * 4) = o;
}

// ---------------------------------------------------------------------------
extern "C" void kernel_launch(void* const* d_in, const int* in_sizes, int n_in,
                              void* d_out, int out_size, void* d_ws, size_t ws_size,
                              hipStream_t stream) {
    const float* state = (const float*)d_in[0];
    const float* W1 = (const float*)d_in[1];
    const float* b1 = (const float*)d_in[2];
    const float* W2 = (const float*)d_in[3];
    const float* b2 = (const float*)d_in[4];
    const float* W3 = (const float*)d_in[5];
    const float* b3 = (const float*)d_in[6];
    const float* qp = (const float*)d_in[7];
    const float* D1 = (const float*)d_in[8];
    const float* d1 = (const float*)d_in[9];
    const float* D2 = (const float*)d_in[10];
    const float* d2 = (const float*)d_in[11];
    const float* D3 = (const float*)d_in[12];
    const float* d3 = (const float*)d_in[13];
    float* out = (float*)d_out;

    const int B = in_sizes[0] / 252;     // 131072

    char* ws = (char*)d_ws;
    _Float16* w1f = (_Float16*)ws;                         // 64 frag-blocks = 64 KB
    _Float16* w2f = (_Float16*)(ws + 65536);               // 16 -> 16 KB
    _Float16* w3f = (_Float16*)(ws + 65536 + 16384);       // 2  -> 2 KB
    float*    enc = (float*)(ws + 65536 + 16384 + 2048);   // B*5 fp32

    prep_all<<<82, 64, 0, stream>>>(W1, W2, W3, w1f, w2f, w3f);
    front_kernel<<<B / (64 * TILES), 256, 0, stream>>>(state, w1f, b1, w2f, b2, w3f, b3, enc);
    back_kernel<<<B / 256, 256, 0, stream>>>(enc, qp, D1, d1, D2, d2, D3, d3, out);
}

// Round 7
// 70.173 us; speedup vs baseline: 1.2380x; 1.2380x over previous
//
#include <hip/hip_runtime.h>
#include <hip/hip_bf16.h>
#include <math.h>

typedef _Float16 half8_t __attribute__((ext_vector_type(8)));
typedef _Float16 half4_t __attribute__((ext_vector_type(4)));
typedef float floatx4 __attribute__((ext_vector_type(4)));

// ---------------------------------------------------------------------------
// K0: repack fp32 weights (K x N row-major) into fp16 MFMA B-fragment layout:
// dst[((nt*KS+ks)*64 + lane)*8 + j] = (half) W[ks*32 + (lane>>4)*8 + j][nt*16 + (lane&15)]
// zero-padded for k >= K or col >= N.  One merged launch for W1/W2/W3.
// ---------------------------------------------------------------------------
__device__ __forceinline__ void prep_body(const float* __restrict__ W,
                                          _Float16* __restrict__ dst,
                                          int K, int N, int KS, int b) {
    int ks   = b % KS;
    int nt   = b / KS;
    int lane = threadIdx.x;         // 64
    int col  = nt * 16 + (lane & 15);
    int kbase = ks * 32 + ((lane >> 4) << 3);
    half8_t v;
#pragma unroll
    for (int j = 0; j < 8; ++j) {
        int k = kbase + j;
        float x = (k < K && col < N) ? W[(size_t)k * N + col] : 0.f;
        v[j] = (_Float16)x;
    }
    *(half8_t*)(dst + (size_t)(b * 64 + lane) * 8) = v;
}

__global__ void prep_all(const float* __restrict__ W1, const float* __restrict__ W2,
                         const float* __restrict__ W3,
                         _Float16* __restrict__ w1f, _Float16* __restrict__ w2f,
                         _Float16* __restrict__ w3f) {
    int b = blockIdx.x;
    if (b < 64)      prep_body(W1, w1f, 252, 128, 8, b);
    else if (b < 80) prep_body(W2, w2f, 128, 64, 4, b - 64);
    else             prep_body(W3, w3f, 64, 5, 2, b - 80);
}

// ---------------------------------------------------------------------------
// K1: front MLP, split-K across wave pairs.
//   512 threads = 8 waves on 64 rows; pair p = w&3 owns N-slice, kh = w>>2
//   owns K-half of every GEMM.  Per-wave B-frags: 8(W1)+2(W2)+1(W3) = 44 VGPR,
//   peak live ~110 -> launch_bounds(512,4): 4 waves/SIMD, 2 blocks/CU.
//   LDS 56KB: sA [64][512B] @0 (fp16, swizzled; becomes reduce region after
//   GEMM1), h1 [64][256B] @32768, h2 [64][128B] @49152.
//   Reduce layouts XOR-swizzled (colL ^ ((row>>2)&3)<<2) -> conflict-free.
//   enc is SoA: enc[i*B + row].
// ---------------------------------------------------------------------------
__global__ __launch_bounds__(512, 4) void front_kernel(
    const float* __restrict__ state,
    const _Float16* __restrict__ w1f, const float* __restrict__ b1,
    const _Float16* __restrict__ w2f, const float* __restrict__ b2,
    const _Float16* __restrict__ w3f, const float* __restrict__ b3,
    float* __restrict__ enc, int Btot) {
    __shared__ char lds[57344];
    const int tid = threadIdx.x;
    const int w   = tid >> 6;
    const int l   = tid & 63;
    const int l15 = l & 15;
    const int lhi = l >> 4;
    const int p   = w & 3;        // pair / N-slice id
    const int kh  = w >> 2;       // K-half id
    const int row0 = blockIdx.x * 64;

    // ---- stage A: all 8 waves; idx -> (row = idx>>6, c8 = idx&63) ----
    // c8 unit = 4 fp32 -> 4 fp16 (8B); c8==63 is the K-pad (cols 252..255).
#pragma unroll
    for (int r8 = 0; r8 < 8; ++r8) {
        int idx = tid + r8 * 512;
        int row = idx >> 6;
        int c8  = idx & 63;
        half4_t h;
        if (c8 == 63) {
            h = half4_t{0, 0, 0, 0};
        } else {
            floatx4 f = *(const floatx4*)(state + (size_t)(row0 + row) * 252 + c8 * 4);
            h = half4_t{ (_Float16)f[0], (_Float16)f[1], (_Float16)f[2], (_Float16)f[3] };
        }
        *(half4_t*)(lds + (row << 9) + ((c8 * 8) ^ ((row & 7) << 4))) = h;
    }

    // ---- B-fragment preload (L2-resident), wave's split-K/N slice only ----
    half8_t bw1[2][4];     // [ntl][ksl], ks = kh*4+ksl, nt = p*2+ntl
#pragma unroll
    for (int ntl = 0; ntl < 2; ++ntl)
#pragma unroll
        for (int ksl = 0; ksl < 4; ++ksl)
            bw1[ntl][ksl] = *(const half8_t*)(w1f + (size_t)(((p * 2 + ntl) * 8 + kh * 4 + ksl) * 64 + l) * 8);
    half8_t bw2[2];        // ks = kh*2+ksl, nt = p
#pragma unroll
    for (int ksl = 0; ksl < 2; ++ksl)
        bw2[ksl] = *(const half8_t*)(w2f + (size_t)((p * 4 + kh * 2 + ksl) * 64 + l) * 8);
    half8_t bw3 = *(const half8_t*)(w3f + (size_t)(kh * 64 + l) * 8);

    __syncthreads();                               // b1: sA ready

    // ---- GEMM1 partial: [64 x 128(K-half)] @ [128 x 32(cols p*32..)] ----
    floatx4 acc1[4][2];
#pragma unroll
    for (int mi = 0; mi < 4; ++mi)
#pragma unroll
        for (int ntl = 0; ntl < 2; ++ntl) acc1[mi][ntl] = floatx4{0, 0, 0, 0};

#pragma unroll
    for (int ksl = 0; ksl < 4; ++ksl) {
        int ks = kh * 4 + ksl;
        half8_t a[4];
#pragma unroll
        for (int mi = 0; mi < 4; ++mi) {
            int r = mi * 16 + l15;
            int cb = ks * 64 + lhi * 16;
            a[mi] = *(const half8_t*)(lds + (r << 9) + (cb ^ ((r & 7) << 4)));
        }
#pragma unroll
        for (int mi = 0; mi < 4; ++mi)
#pragma unroll
            for (int ntl = 0; ntl < 2; ++ntl)
                acc1[mi][ntl] = __builtin_amdgcn_mfma_f32_16x16x32_f16(a[mi], bw1[ntl][ksl], acc1[mi][ntl], 0, 0, 0);
    }
    __syncthreads();                               // b2: sA dead

    // ---- red1: kh==1 writes partials to LDS @0 (pair p: 64x32 f32) ----
    if (kh) {
        char* base = lds + p * 8192;
#pragma unroll
        for (int mi = 0; mi < 4; ++mi)
#pragma unroll
            for (int ntl = 0; ntl < 2; ++ntl)
#pragma unroll
                for (int ri = 0; ri < 4; ++ri) {
                    int row = mi * 16 + lhi * 4 + ri;
                    int word = row * 32 + ((ntl * 16 + l15) ^ (((row >> 2) & 3) << 2));
                    *(float*)(base + word * 4) = acc1[mi][ntl][ri];
                }
    }
    __syncthreads();                               // b3

    // ---- combine + h1 = relu(.. + b1) -> LDS @32768 (kh==0 only) ----
    if (!kh) {
        char* base = lds + p * 8192;
#pragma unroll
        for (int ntl = 0; ntl < 2; ++ntl) {
            int col = p * 32 + ntl * 16 + l15;
            float bb = b1[col];
#pragma unroll
            for (int mi = 0; mi < 4; ++mi)
#pragma unroll
                for (int ri = 0; ri < 4; ++ri) {
                    int row = mi * 16 + lhi * 4 + ri;
                    int word = row * 32 + ((ntl * 16 + l15) ^ (((row >> 2) & 3) << 2));
                    float v = acc1[mi][ntl][ri] + *(float*)(base + word * 4) + bb;
                    v = v > 0.f ? v : 0.f;
                    *(_Float16*)(lds + 32768 + (row << 8) + ((col * 2) ^ ((row & 7) << 4))) = (_Float16)v;
                }
        }
    }
    __syncthreads();                               // b4: h1 ready

    // ---- GEMM2 partial: [64 x 64(K-half)] @ [64 x 16(cols p*16..)] ----
    floatx4 acc2[4];
#pragma unroll
    for (int mi = 0; mi < 4; ++mi) acc2[mi] = floatx4{0, 0, 0, 0};
#pragma unroll
    for (int ksl = 0; ksl < 2; ++ksl) {
        int ks = kh * 2 + ksl;
#pragma unroll
        for (int mi = 0; mi < 4; ++mi) {
            int r = mi * 16 + l15;
            int cb = ks * 64 + lhi * 16;
            half8_t a = *(const half8_t*)(lds + 32768 + (r << 8) + (cb ^ ((r & 7) << 4)));
            acc2[mi] = __builtin_amdgcn_mfma_f32_16x16x32_f16(a, bw2[ksl], acc2[mi], 0, 0, 0);
        }
    }
    // ---- red2: kh==1 writes partials @0 (pair p: 64x16 f32) ----
    if (kh) {
        char* base = lds + p * 4096;
#pragma unroll
        for (int mi = 0; mi < 4; ++mi)
#pragma unroll
            for (int ri = 0; ri < 4; ++ri) {
                int row = mi * 16 + lhi * 4 + ri;
                int word = row * 16 + (l15 ^ (((row >> 2) & 3) << 2));
                *(float*)(base + word * 4) = acc2[mi][ri];
            }
    }
    __syncthreads();                               // b5

    // ---- combine + h2 = relu(.. + b2) -> LDS @49152 (kh==0 only) ----
    if (!kh) {
        char* base = lds + p * 4096;
        int col = p * 16 + l15;
        float bb = b2[col];
#pragma unroll
        for (int mi = 0; mi < 4; ++mi)
#pragma unroll
            for (int ri = 0; ri < 4; ++ri) {
                int row = mi * 16 + lhi * 4 + ri;
                int word = row * 16 + (l15 ^ (((row >> 2) & 3) << 2));
                float v = acc2[mi][ri] + *(float*)(base + word * 4) + bb;
                v = v > 0.f ? v : 0.f;
                *(_Float16*)(lds + 49152 + (row << 7) + ((col * 2) ^ ((row & 7) << 4))) = (_Float16)v;
            }
    }
    __syncthreads();                               // b6: h2 ready

    // ---- GEMM3 partial: pair p rows p*16..+15, K-half kh ----
    floatx4 acc3;
    {
        int r = p * 16 + l15;
        int cb = kh * 64 + lhi * 16;
        half8_t a = *(const half8_t*)(lds + 49152 + (r << 7) + (cb ^ ((r & 7) << 4)));
        acc3 = __builtin_amdgcn_mfma_f32_16x16x32_f16(a, bw3, floatx4{0, 0, 0, 0}, 0, 0, 0);
    }
    // ---- red3: kh==1 writes partials @16384 (pair p: 16x16 f32) ----
    if (kh) {
        char* base = lds + 16384 + p * 1024;
#pragma unroll
        for (int ri = 0; ri < 4; ++ri) {
            int rowL = lhi * 4 + ri;
            int word = rowL * 16 + (l15 ^ (((rowL >> 2) & 3) << 2));
            *(float*)(base + word * 4) = acc3[ri];
        }
    }
    __syncthreads();                               // b7

    // ---- combine + enc = tanh(.. + b3), SoA enc[i*B + row] ----
    if (!kh && l15 < 5) {
        char* base = lds + 16384 + p * 1024;
        float bb = b3[l15];
#pragma unroll
        for (int ri = 0; ri < 4; ++ri) {
            int rowL = lhi * 4 + ri;
            int word = rowL * 16 + (l15 ^ (((rowL >> 2) & 3) << 2));
            float v = acc3[ri] + *(float*)(base + word * 4) + bb;
            enc[(size_t)l15 * Btot + row0 + p * 16 + rowL] = tanhf(v);
        }
    }
}

// ---------------------------------------------------------------------------
// K2: quantum circuit + back MLP, one thread per batch row.
// wire w <-> bit (4-w) of the flat amplitude index (wire 0 = MSB).
// ---------------------------------------------------------------------------
template<int P>
__device__ __forceinline__ void ry_g(float* re, float* im, float c, float s) {
    constexpr int STR = 1 << P;
#pragma unroll
    for (int base = 0; base < 32; base += 2 * STR)
#pragma unroll
        for (int d = 0; d < STR; ++d) {
            int i0 = base + d, i1 = i0 + STR;
            float r0 = re[i0], r1 = re[i1], m0 = im[i0], m1 = im[i1];
            re[i0] = c * r0 - s * r1;  re[i1] = s * r0 + c * r1;
            im[i0] = c * m0 - s * m1;  im[i1] = s * m0 + c * m1;
        }
}

template<int P>
__device__ __forceinline__ void rz_g(float* re, float* im, float c, float s) {
#pragma unroll
    for (int i = 0; i < 32; ++i) {
        float t = ((i >> P) & 1) ? s : -s;    // bit0: e^{-i h}, bit1: e^{+i h}
        float r = re[i], m = im[i];
        re[i] = c * r - t * m;
        im[i] = c * m + t * r;
    }
}

template<int PC, int PT>
__device__ __forceinline__ void cnot_g(float* re, float* im) {
#pragma unroll
    for (int i = 0; i < 32; ++i) {
        if (((i >> PC) & 1) && !((i >> PT) & 1)) {
            int j = i | (1 << PT);
            float t;
            t = re[i]; re[i] = re[j]; re[j] = t;
            t = im[i]; im[i] = im[j]; im[j] = t;
        }
    }
}

__global__ __launch_bounds__(256) void back_kernel(
    const float* __restrict__ enc, const float* __restrict__ qp,
    const float* __restrict__ D1, const float* __restrict__ d1,
    const float* __restrict__ D2, const float* __restrict__ d2,
    const float* __restrict__ D3, const float* __restrict__ d3,
    float* __restrict__ out, int Btot) {
    __shared__ float sD1[160], sd1[32], sD2[512], sd2[16], sD3[64], sd3[4];
    __shared__ float sQc[30], sQs[30];
    const int tid = threadIdx.x;
    for (int i = tid; i < 512; i += 256) sD2[i] = D2[i];
    if (tid < 160) sD1[tid] = D1[tid];
    if (tid < 32)  sd1[tid] = d1[tid];
    if (tid < 64)  sD3[tid] = D3[tid];
    if (tid < 16)  sd2[tid] = d2[tid];
    if (tid < 4)   sd3[tid] = d3[tid];
    if (tid < 30) { float h = 0.5f * qp[tid]; sQc[tid] = cosf(h); sQs[tid] = sinf(h); }
    __syncthreads();

    const size_t r = (size_t)blockIdx.x * 256 + tid;

    // encoding: product state from RY(enc_i * pi) on |0...0>; enc is SoA.
    float cq[5], sq[5];
    const float HPI = 1.57079632679489662f;   // pi/2
#pragma unroll
    for (int i = 0; i < 5; ++i) {
        float a = enc[(size_t)i * Btot + r] * HPI;
        cq[i] = cosf(a);
        sq[i] = sinf(a);
    }
    float re[32], im[32];
#pragma unroll
    for (int i = 0; i < 32; ++i) {
        float v = ((i >> 4) & 1) ? sq[0] : cq[0];
        v *= ((i >> 3) & 1) ? sq[1] : cq[1];
        v *= ((i >> 2) & 1) ? sq[2] : cq[2];
        v *= ((i >> 1) & 1) ? sq[3] : cq[3];
        v *= ( i       & 1) ? sq[4] : cq[4];
        re[i] = v;
        im[i] = 0.f;
    }

#pragma unroll
    for (int lay = 0; lay < 3; ++lay) {
        const float* c = sQc + lay * 10;
        const float* s = sQs + lay * 10;
        ry_g<4>(re, im, c[0], s[0]);  rz_g<4>(re, im, c[1], s[1]);
        ry_g<3>(re, im, c[2], s[2]);  rz_g<3>(re, im, c[3], s[3]);
        ry_g<2>(re, im, c[4], s[4]);  rz_g<2>(re, im, c[5], s[5]);
        ry_g<1>(re, im, c[6], s[6]);  rz_g<1>(re, im, c[7], s[7]);
        ry_g<0>(re, im, c[8], s[8]);  rz_g<0>(re, im, c[9], s[9]);
        cnot_g<4, 3>(re, im);
        cnot_g<3, 2>(re, im);
        cnot_g<2, 1>(re, im);
        cnot_g<1, 0>(re, im);
    }

    float q[5] = {0, 0, 0, 0, 0};
#pragma unroll
    for (int i = 0; i < 32; ++i) {
        float p = re[i] * re[i] + im[i] * im[i];
        q[0] += ((i >> 4) & 1) ? -p : p;
        q[1] += ((i >> 3) & 1) ? -p : p;
        q[2] += ((i >> 2) & 1) ? -p : p;
        q[3] += ((i >> 1) & 1) ? -p : p;
        q[4] += ( i       & 1) ? -p : p;
    }

    // back MLP: q(5) -> 32 relu -> 16 relu -> 4
    float h1[32];
#pragma unroll
    for (int j = 0; j < 32; ++j) {
        float a = sd1[j];
#pragma unroll
        for (int k = 0; k < 5; ++k) a += q[k] * sD1[k * 32 + j];
        h1[j] = a > 0.f ? a : 0.f;
    }
    float h2[16];
#pragma unroll
    for (int j = 0; j < 16; ++j) {
        float a = sd2[j];
#pragma unroll
        for (int k = 0; k < 32; ++k) a += h1[k] * sD2[k * 16 + j];
        h2[j] = a > 0.f ? a : 0.f;
    }
    floatx4 o;
#pragma unroll
    for (int j = 0; j < 4; ++j) {
        float a = sd3[j];
#pragma unroll
        for (int k = 0; k < 16; ++k) a += h2[k] * sD3[k * 4 + j];
        o[j] = a;
    }
    *(floatx4*)(out + r * 4) = o;
}

// ---------------------------------------------------------------------------
extern "C" void kernel_launch(void* const* d_in, const int* in_sizes, int n_in,
                              void* d_out, int out_size, void* d_ws, size_t ws_size,
                              hipStream_t stream) {
    const float* state = (const float*)d_in[0];
    const float* W1 = (const float*)d_in[1];
    const float* b1 = (const float*)d_in[2];
    const float* W2 = (const float*)d_in[3];
    const float* b2 = (const float*)d_in[4];
    const float* W3 = (const float*)d_in[5];
    const float* b3 = (const float*)d_in[6];
    const float* qp = (const float*)d_in[7];
    const float* D1 = (const float*)d_in[8];
    const float* d1 = (const float*)d_in[9];
    const float* D2 = (const float*)d_in[10];
    const float* d2 = (const float*)d_in[11];
    const float* D3 = (const float*)d_in[12];
    const float* d3 = (const float*)d_in[13];
    float* out = (float*)d_out;

    const int B = in_sizes[0] / 252;     // 131072

    char* ws = (char*)d_ws;
    _Float16* w1f = (_Float16*)ws;                         // 64 frag-blocks = 64 KB
    _Float16* w2f = (_Float16*)(ws + 65536);               // 16 -> 16 KB
    _Float16* w3f = (_Float16*)(ws + 65536 + 16384);       // 2  -> 2 KB
    float*    enc = (float*)(ws + 65536 + 16384 + 2048);   // SoA [5][B] fp32

    prep_all<<<82, 64, 0, stream>>>(W1, W2, W3, w1f, w2f, w3f);
    front_kernel<<<B / 64, 512, 0, stream>>>(state, w1f, b1, w2f, b2, w3f, b3, enc, B);
    back_kernel<<<B / 256, 256, 0, stream>>>(enc, qp, D1, d1, D2, d2, D3, d3, out, B);
}

// Round 8
// 56.463 us; speedup vs baseline: 1.5386x; 1.2428x over previous
//
#include <hip/hip_runtime.h>
#include <hip/hip_bf16.h>
#include <math.h>

typedef _Float16 half8_t __attribute__((ext_vector_type(8)));
typedef _Float16 half4_t __attribute__((ext_vector_type(4)));
typedef float floatx4 __attribute__((ext_vector_type(4)));

#define TPT 8   // 32-row tiles per block; grid = B/(32*TPT) = 512 = 2 blocks/CU

// LDS barrier that does NOT drain vmcnt: cross-wave ordering here is only
// through LDS (global traffic is read-only input + private enc stores), so
// draining lgkmcnt before s_barrier is sufficient.  Keeping vmcnt alive is
// what lets the cross-tile A-prefetch stay in flight across barriers.
__device__ __forceinline__ void lds_barrier() {
    asm volatile("s_waitcnt lgkmcnt(0)" ::: "memory");
    __builtin_amdgcn_s_barrier();
    asm volatile("" ::: "memory");
}

__device__ __forceinline__ float fast_tanh(float x) {
    float e = __expf(2.f * x);
    return 1.f - 2.f / (e + 1.f);
}

// ---------------------------------------------------------------------------
// K0: repack fp32 weights (K x N row-major) into fp16 MFMA B-fragment layout:
// dst[((nt*KS+ks)*64 + lane)*8 + j] = (half) W[ks*32 + (lane>>4)*8 + j][nt*16 + (lane&15)]
// ---------------------------------------------------------------------------
__device__ __forceinline__ void prep_body(const float* __restrict__ W,
                                          _Float16* __restrict__ dst,
                                          int K, int N, int KS, int b) {
    int ks   = b % KS;
    int nt   = b / KS;
    int lane = threadIdx.x;         // 64
    int col  = nt * 16 + (lane & 15);
    int kbase = ks * 32 + ((lane >> 4) << 3);
    half8_t v;
#pragma unroll
    for (int j = 0; j < 8; ++j) {
        int k = kbase + j;
        float x = (k < K && col < N) ? W[(size_t)k * N + col] : 0.f;
        v[j] = (_Float16)x;
    }
    *(half8_t*)(dst + (size_t)(b * 64 + lane) * 8) = v;
}

__global__ void prep_all(const float* __restrict__ W1, const float* __restrict__ W2,
                         const float* __restrict__ W3,
                         _Float16* __restrict__ w1f, _Float16* __restrict__ w2f,
                         _Float16* __restrict__ w3f) {
    int b = blockIdx.x;
    if (b < 64)      prep_body(W1, w1f, 252, 128, 8, b);
    else if (b < 80) prep_body(W2, w2f, 128, 64, 4, b - 64);
    else             prep_body(W3, w3f, 64, 5, 2, b - 80);
}

// ---------------------------------------------------------------------------
// K1: front MLP.  512 blocks x 256 thr (4 waves), each block runs TPT=8
// tiles of 32 rows.  B-fragments register-resident (loaded ONCE per block).
// Cross-tile prefetch: tile t+1's A (8 x fp32x4 per thread) is issued right
// after tile t's staging consumes pf, and stays in flight across the whole
// tile-t compute (lds_barrier never drains vmcnt).
//   N-split: wave w -> GEMM1 cols w*32..+31, GEMM2 cols w*16..+15;
//   GEMM3 (tiny): waves 0,1 -> rows 0..15 / 16..31.
//   LDS 28KB: sA [32][512B] @0, h1 [32][256B] @16384, h2 [32][128B] @24576,
//   all XOR-swizzled (byte ^= (row&7)<<4 on 16B units).
// ---------------------------------------------------------------------------
__global__ __launch_bounds__(256, 2) void front_kernel(
    const float* __restrict__ state,
    const _Float16* __restrict__ w1f, const float* __restrict__ b1,
    const _Float16* __restrict__ w2f, const float* __restrict__ b2,
    const _Float16* __restrict__ w3f, const float* __restrict__ b3,
    float* __restrict__ enc, int Btot) {
    __shared__ char lds[28672];
    const int tid = threadIdx.x;
    const int w   = tid >> 6;
    const int l   = tid & 63;
    const int l15 = l & 15;
    const int lhi = l >> 4;
    const int row0 = blockIdx.x * (32 * TPT);

    // staging geometry: thread -> (srow = tid>>3, chunks c = (tid&7)+8j),
    // chunk = 16B of global fp32 (4 cols) -> 8B of LDS fp16.  c==63 is K-pad.
    const int srow = tid >> 3;
    const int sc0  = tid & 7;
    const int sswz = (srow & 7) << 4;

    floatx4 pf[8];   // prefetched A chunks for the NEXT tile (32 VGPR)

#define ISSUE_A(T)                                                          \
    {                                                                       \
        const float* Ar = state + (size_t)(row0 + (T) * 32 + srow) * 252;   \
        _Pragma("unroll")                                                   \
        for (int jj = 0; jj < 8; ++jj) {                                    \
            int c = sc0 + jj * 8;                                           \
            if (c < 63) pf[jj] = *(const floatx4*)(Ar + c * 4);             \
        }                                                                   \
    }

    ISSUE_A(0)

    // ---- B-fragment preload (once per block; L2-resident) ----
    half8_t bw1[2][8], bw2[4], bw3[2];
#pragma unroll
    for (int ntl = 0; ntl < 2; ++ntl)
#pragma unroll
        for (int ks = 0; ks < 8; ++ks)
            bw1[ntl][ks] = *(const half8_t*)(w1f + (size_t)(((w * 2 + ntl) * 8 + ks) * 64 + l) * 8);
#pragma unroll
    for (int ks = 0; ks < 4; ++ks)
        bw2[ks] = *(const half8_t*)(w2f + (size_t)((w * 4 + ks) * 64 + l) * 8);
#pragma unroll
    for (int ks = 0; ks < 2; ++ks)
        bw3[ks] = *(const half8_t*)(w3f + (size_t)(ks * 64 + l) * 8);

#pragma unroll 1
    for (int t = 0; t < TPT; ++t) {
        // ---- stage: pf -> sA (cvt fp32->fp16, swizzled) ----
#pragma unroll
        for (int jj = 0; jj < 8; ++jj) {
            int c = sc0 + jj * 8;
            half4_t h;
            if (c == 63) {
                h = half4_t{0, 0, 0, 0};            // K-pad cols 252..255
            } else {
                floatx4 f = pf[jj];
                h = half4_t{ (_Float16)f[0], (_Float16)f[1], (_Float16)f[2], (_Float16)f[3] };
            }
            *(half4_t*)(lds + (srow << 9) + ((c * 8) ^ sswz)) = h;
        }
        // ---- issue next tile's loads: in flight across ALL of tile t ----
        if (t + 1 < TPT) ISSUE_A(t + 1)
        lds_barrier();                               // sA ready (vmcnt alive)

        // ---- GEMM1: [32 x 256] @ [256 x 32(cols w*32..)] ----
        floatx4 acc1[2][2];
#pragma unroll
        for (int mi = 0; mi < 2; ++mi)
#pragma unroll
            for (int ntl = 0; ntl < 2; ++ntl) acc1[mi][ntl] = floatx4{0, 0, 0, 0};
#pragma unroll
        for (int ks = 0; ks < 8; ++ks) {
            half8_t a[2];
#pragma unroll
            for (int mi = 0; mi < 2; ++mi) {
                int r = mi * 16 + l15;
                int cb = ks * 64 + lhi * 16;
                a[mi] = *(const half8_t*)(lds + (r << 9) + (cb ^ ((r & 7) << 4)));
            }
#pragma unroll
            for (int mi = 0; mi < 2; ++mi)
#pragma unroll
                for (int ntl = 0; ntl < 2; ++ntl)
                    acc1[mi][ntl] = __builtin_amdgcn_mfma_f32_16x16x32_f16(a[mi], bw1[ntl][ks], acc1[mi][ntl], 0, 0, 0);
        }

        // ---- h1 = relu(acc1 + b1) -> LDS @16384 (own region) ----
#pragma unroll
        for (int ntl = 0; ntl < 2; ++ntl) {
            int col = (w * 2 + ntl) * 16 + l15;
            float bb = b1[col];
#pragma unroll
            for (int mi = 0; mi < 2; ++mi)
#pragma unroll
                for (int ri = 0; ri < 4; ++ri) {
                    int row = mi * 16 + lhi * 4 + ri;
                    float v = acc1[mi][ntl][ri] + bb;
                    v = v > 0.f ? v : 0.f;
                    *(_Float16*)(lds + 16384 + (row << 8) + ((col * 2) ^ ((row & 7) << 4))) = (_Float16)v;
                }
        }
        lds_barrier();                               // h1 ready

        // ---- GEMM2: [32 x 128] @ [128 x 16(cols w*16..)] ----
        floatx4 acc2[2];
#pragma unroll
        for (int mi = 0; mi < 2; ++mi) acc2[mi] = floatx4{0, 0, 0, 0};
#pragma unroll
        for (int ks = 0; ks < 4; ++ks)
#pragma unroll
            for (int mi = 0; mi < 2; ++mi) {
                int r = mi * 16 + l15;
                int cb = ks * 64 + lhi * 16;
                half8_t a = *(const half8_t*)(lds + 16384 + (r << 8) + (cb ^ ((r & 7) << 4)));
                acc2[mi] = __builtin_amdgcn_mfma_f32_16x16x32_f16(a, bw2[ks], acc2[mi], 0, 0, 0);
            }

        // ---- h2 = relu(acc2 + b2) -> LDS @24576 (own region) ----
        {
            int col = w * 16 + l15;
            float bb = b2[col];
#pragma unroll
            for (int mi = 0; mi < 2; ++mi)
#pragma unroll
                for (int ri = 0; ri < 4; ++ri) {
                    int row = mi * 16 + lhi * 4 + ri;
                    float v = acc2[mi][ri] + bb;
                    v = v > 0.f ? v : 0.f;
                    *(_Float16*)(lds + 24576 + (row << 7) + ((col * 2) ^ ((row & 7) << 4))) = (_Float16)v;
                }
        }
        lds_barrier();                               // h2 ready

        // ---- GEMM3: [32 x 64] @ [64 x 16] -> waves 0,1 (rows w*16..) ----
        if (w < 2) {
            floatx4 acc3 = floatx4{0, 0, 0, 0};
#pragma unroll
            for (int ks = 0; ks < 2; ++ks) {
                int r = w * 16 + l15;
                int cb = ks * 64 + lhi * 16;
                half8_t a = *(const half8_t*)(lds + 24576 + (r << 7) + (cb ^ ((r & 7) << 4)));
                acc3 = __builtin_amdgcn_mfma_f32_16x16x32_f16(a, bw3[ks], acc3, 0, 0, 0);
            }
            if (l15 < 5) {
                float bb = b3[l15];
#pragma unroll
                for (int ri = 0; ri < 4; ++ri) {
                    int grow = row0 + t * 32 + w * 16 + lhi * 4 + ri;
                    enc[(size_t)l15 * Btot + grow] = fast_tanh(acc3[ri] + bb);
                }
            }
        }
        // next iteration's stage writes sA: all waves passed h2-barrier, and
        // sA was last read before the h1-barrier -> race-free.
    }
#undef ISSUE_A
}

// ---------------------------------------------------------------------------
// K2: quantum circuit + back MLP, one thread per batch row.
// ---------------------------------------------------------------------------
template<int P>
__device__ __forceinline__ void ry_g(float* re, float* im, float c, float s) {
    constexpr int STR = 1 << P;
#pragma unroll
    for (int base = 0; base < 32; base += 2 * STR)
#pragma unroll
        for (int d = 0; d < STR; ++d) {
            int i0 = base + d, i1 = i0 + STR;
            float r0 = re[i0], r1 = re[i1], m0 = im[i0], m1 = im[i1];
            re[i0] = c * r0 - s * r1;  re[i1] = s * r0 + c * r1;
            im[i0] = c * m0 - s * m1;  im[i1] = s * m0 + c * m1;
        }
}

template<int P>
__device__ __forceinline__ void rz_g(float* re, float* im, float c, float s) {
#pragma unroll
    for (int i = 0; i < 32; ++i) {
        float t = ((i >> P) & 1) ? s : -s;
        float r = re[i], m = im[i];
        re[i] = c * r - t * m;
        im[i] = c * m + t * r;
    }
}

template<int PC, int PT>
__device__ __forceinline__ void cnot_g(float* re, float* im) {
#pragma unroll
    for (int i = 0; i < 32; ++i) {
        if (((i >> PC) & 1) && !((i >> PT) & 1)) {
            int j = i | (1 << PT);
            float t;
            t = re[i]; re[i] = re[j]; re[j] = t;
            t = im[i]; im[i] = im[j]; im[j] = t;
        }
    }
}

__global__ __launch_bounds__(256) void back_kernel(
    const float* __restrict__ enc, const float* __restrict__ qp,
    const float* __restrict__ D1, const float* __restrict__ d1,
    const float* __restrict__ D2, const float* __restrict__ d2,
    const float* __restrict__ D3, const float* __restrict__ d3,
    float* __restrict__ out, int Btot) {
    __shared__ float sD1[160], sd1[32], sD2[512], sd2[16], sD3[64], sd3[4];
    __shared__ float sQc[30], sQs[30];
    const int tid = threadIdx.x;
    for (int i = tid; i < 512; i += 256) sD2[i] = D2[i];
    if (tid < 160) sD1[tid] = D1[tid];
    if (tid < 32)  sd1[tid] = d1[tid];
    if (tid < 64)  sD3[tid] = D3[tid];
    if (tid < 16)  sd2[tid] = d2[tid];
    if (tid < 4)   sd3[tid] = d3[tid];
    if (tid < 30) { float h = 0.5f * qp[tid]; sQc[tid] = cosf(h); sQs[tid] = sinf(h); }
    __syncthreads();

    const size_t r = (size_t)blockIdx.x * 256 + tid;

    float cq[5], sq[5];
    const float HPI = 1.57079632679489662f;   // pi/2
#pragma unroll
    for (int i = 0; i < 5; ++i) {
        float a = enc[(size_t)i * Btot + r] * HPI;
        cq[i] = __cosf(a);
        sq[i] = __sinf(a);
    }
    float re[32], im[32];
#pragma unroll
    for (int i = 0; i < 32; ++i) {
        float v = ((i >> 4) & 1) ? sq[0] : cq[0];
        v *= ((i >> 3) & 1) ? sq[1] : cq[1];
        v *= ((i >> 2) & 1) ? sq[2] : cq[2];
        v *= ((i >> 1) & 1) ? sq[3] : cq[3];
        v *= ( i       & 1) ? sq[4] : cq[4];
        re[i] = v;
        im[i] = 0.f;
    }

#pragma unroll
    for (int lay = 0; lay < 3; ++lay) {
        const float* c = sQc + lay * 10;
        const float* s = sQs + lay * 10;
        ry_g<4>(re, im, c[0], s[0]);  rz_g<4>(re, im, c[1], s[1]);
        ry_g<3>(re, im, c[2], s[2]);  rz_g<3>(re, im, c[3], s[3]);
        ry_g<2>(re, im, c[4], s[4]);  rz_g<2>(re, im, c[5], s[5]);
        ry_g<1>(re, im, c[6], s[6]);  rz_g<1>(re, im, c[7], s[7]);
        ry_g<0>(re, im, c[8], s[8]);  rz_g<0>(re, im, c[9], s[9]);
        cnot_g<4, 3>(re, im);
        cnot_g<3, 2>(re, im);
        cnot_g<2, 1>(re, im);
        cnot_g<1, 0>(re, im);
    }

    float q[5] = {0, 0, 0, 0, 0};
#pragma unroll
    for (int i = 0; i < 32; ++i) {
        float p = re[i] * re[i] + im[i] * im[i];
        q[0] += ((i >> 4) & 1) ? -p : p;
        q[1] += ((i >> 3) & 1) ? -p : p;
        q[2] += ((i >> 2) & 1) ? -p : p;
        q[3] += ((i >> 1) & 1) ? -p : p;
        q[4] += ( i       & 1) ? -p : p;
    }

    float h1[32];
#pragma unroll
    for (int j = 0; j < 32; ++j) {
        float a = sd1[j];
#pragma unroll
        for (int k = 0; k < 5; ++k) a += q[k] * sD1[k * 32 + j];
        h1[j] = a > 0.f ? a : 0.f;
    }
    float h2[16];
#pragma unroll
    for (int j = 0; j < 16; ++j) {
        float a = sd2[j];
#pragma unroll
        for (int k = 0; k < 32; ++k) a += h1[k] * sD2[k * 16 + j];
        h2[j] = a > 0.f ? a : 0.f;
    }
    floatx4 o;
#pragma unroll
    for (int j = 0; j < 4; ++j) {
        float a = sd3[j];
#pragma unroll
        for (int k = 0; k < 16; ++k) a += h2[k] * sD3[k * 4 + j];
        o[j] = a;
    }
    *(floatx4*)(out + r * 4) = o;
}

// ---------------------------------------------------------------------------
extern "C" void kernel_launch(void* const* d_in, const int* in_sizes, int n_in,
                              void* d_out, int out_size, void* d_ws, size_t ws_size,
                              hipStream_t stream) {
    const float* state = (const float*)d_in[0];
    const float* W1 = (const float*)d_in[1];
    const float* b1 = (const float*)d_in[2];
    const float* W2 = (const float*)d_in[3];
    const float* b2 = (const float*)d_in[4];
    const float* W3 = (const float*)d_in[5];
    const float* b3 = (const float*)d_in[6];
    const float* qp = (const float*)d_in[7];
    const float* D1 = (const float*)d_in[8];
    const float* d1 = (const float*)d_in[9];
    const float* D2 = (const float*)d_in[10];
    const float* d2 = (const float*)d_in[11];
    const float* D3 = (const float*)d_in[12];
    const float* d3 = (const float*)d_in[13];
    float* out = (float*)d_out;

    const int B = in_sizes[0] / 252;     // 131072

    char* ws = (char*)d_ws;
    _Float16* w1f = (_Float16*)ws;                         // 64 KB
    _Float16* w2f = (_Float16*)(ws + 65536);               // 16 KB
    _Float16* w3f = (_Float16*)(ws + 65536 + 16384);       // 2 KB
    float*    enc = (float*)(ws + 65536 + 16384 + 2048);   // SoA [5][B] fp32

    prep_all<<<82, 64, 0, stream>>>(W1, W2, W3, w1f, w2f, w3f);
    front_kernel<<<B / (32 * TPT), 256, 0, stream>>>(state, w1f, b1, w2f, b2, w3f, b3, enc, B);
    back_kernel<<<B / 256, 256, 0, stream>>>(enc, qp, D1, d1, D2, d2, D3, d3, out, B);
}

// Round 9
// 55.783 us; speedup vs baseline: 1.5573x; 1.0122x over previous
//
#include <hip/hip_runtime.h>
#include <hip/hip_bf16.h>
#include <math.h>

typedef _Float16 half8_t __attribute__((ext_vector_type(8)));
typedef _Float16 half4_t __attribute__((ext_vector_type(4)));
typedef float floatx4 __attribute__((ext_vector_type(4)));

#define TPT 8   // 32-row tiles per block; grid = B/(32*TPT) = 512 = 2 blocks/CU

// LDS barrier that does NOT drain vmcnt: cross-wave ordering here is only
// through LDS (global traffic is read-only input + private enc stores), so
// draining lgkmcnt before s_barrier is sufficient.  Keeping vmcnt alive lets
// the cross-tile A-prefetch stay in flight across barriers.
__device__ __forceinline__ void lds_barrier() {
    asm volatile("s_waitcnt lgkmcnt(0)" ::: "memory");
    __builtin_amdgcn_s_barrier();
    asm volatile("" ::: "memory");
}

__device__ __forceinline__ float fast_tanh(float x) {
    float e = __expf(2.f * x);
    return 1.f - 2.f / (e + 1.f);
}

// ---------------------------------------------------------------------------
// K0: repack fp32 weights (K x N row-major) into fp16 MFMA B-fragment layout:
// dst[((nt*KS+ks)*64 + lane)*8 + j] = (half) W[ks*32 + (lane>>4)*8 + j][nt*16 + (lane&15)]
// ---------------------------------------------------------------------------
__device__ __forceinline__ void prep_body(const float* __restrict__ W,
                                          _Float16* __restrict__ dst,
                                          int K, int N, int KS, int b) {
    int ks   = b % KS;
    int nt   = b / KS;
    int lane = threadIdx.x;         // 64
    int col  = nt * 16 + (lane & 15);
    int kbase = ks * 32 + ((lane >> 4) << 3);
    half8_t v;
#pragma unroll
    for (int j = 0; j < 8; ++j) {
        int k = kbase + j;
        float x = (k < K && col < N) ? W[(size_t)k * N + col] : 0.f;
        v[j] = (_Float16)x;
    }
    *(half8_t*)(dst + (size_t)(b * 64 + lane) * 8) = v;
}

__global__ void prep_all(const float* __restrict__ W1, const float* __restrict__ W2,
                         const float* __restrict__ W3,
                         _Float16* __restrict__ w1f, _Float16* __restrict__ w2f,
                         _Float16* __restrict__ w3f) {
    int b = blockIdx.x;
    if (b < 64)      prep_body(W1, w1f, 252, 128, 8, b);
    else if (b < 80) prep_body(W2, w2f, 128, 64, 4, b - 64);
    else             prep_body(W3, w3f, 64, 5, 2, b - 80);
}

// ---------------------------------------------------------------------------
// K1: front MLP.  512 blocks x 512 thr (8 waves), TPT=8 tiles of 32 rows.
// Work split (NO split-K):
//   GEMM1 [32x256]@[256x128]: wave w -> cols w*16..+15  (8 W1 frags in VGPR)
//   GEMM2 [32x128]@[128x64] : wave w -> (mi=w>>2)x(nt=w&3) 16x16 out tile,
//                             B-frags read from LDS (copied once per block)
//   GEMM3 [32x64]@[64x16]   : waves 0,1 -> rows w*16..+15, B from LDS
// Cross-tile prefetch: tile t+1's A (4 x fp32x4/thread = 16 VGPR) issued
// right after tile t's staging; lds_barrier never drains vmcnt.
//   LDS 46KB: sA [32][512B]@0, h1 [32][256B]@16384, h2 [32][128B]@24576,
//   W2 frags 16KB@28672, W3 frags 2KB@45056.  XOR swizzle on all tiles.
// Per-wave VGPR ~100 -> launch_bounds(512,4): 4 waves/SIMD, 2 blocks/CU.
// ---------------------------------------------------------------------------
__global__ __launch_bounds__(512, 4) void front_kernel(
    const float* __restrict__ state,
    const _Float16* __restrict__ w1f, const float* __restrict__ b1,
    const _Float16* __restrict__ w2f, const float* __restrict__ b2,
    const _Float16* __restrict__ w3f, const float* __restrict__ b3,
    float* __restrict__ enc, int Btot) {
    __shared__ char lds[47104];
    const int tid = threadIdx.x;    // 0..511
    const int w   = tid >> 6;       // 0..7
    const int l   = tid & 63;
    const int l15 = l & 15;
    const int lhi = l >> 4;
    const int row0 = blockIdx.x * (32 * TPT);

    // staging geometry: thread -> (srow = tid>>4, chunks c = (tid&15)+16j);
    // chunk = 16B global fp32 (4 cols) -> 8B LDS fp16.  c==63 is the K-pad.
    const int srow = tid >> 4;
    const int sc0  = tid & 15;
    const int sswz = (srow & 7) << 4;

    floatx4 pf[4];   // prefetched A chunks for the NEXT tile (16 VGPR)

#define ISSUE_A(T)                                                          \
    {                                                                       \
        const float* Ar = state + (size_t)(row0 + (T) * 32 + srow) * 252;   \
        _Pragma("unroll")                                                   \
        for (int jj = 0; jj < 4; ++jj) {                                    \
            int c = sc0 + jj * 16;                                          \
            if (c < 63) pf[jj] = *(const floatx4*)(Ar + c * 4);             \
        }                                                                   \
    }

    ISSUE_A(0)

    // ---- W1 B-frags for this wave's N-slice (nt = w): 8 frags, 32 VGPR ----
    half8_t bw1[8];
#pragma unroll
    for (int ks = 0; ks < 8; ++ks)
        bw1[ks] = *(const half8_t*)(w1f + (size_t)((w * 8 + ks) * 64 + l) * 8);

    // ---- copy W2/W3 fragment data into LDS (once per block) ----
    {
        const floatx4* s2 = (const floatx4*)w2f;          // 1024 x 16B
        *(floatx4*)(lds + 28672 + tid * 16)        = s2[tid];
        *(floatx4*)(lds + 28672 + 8192 + tid * 16) = s2[512 + tid];
        if (tid < 128) {
            const floatx4* s3 = (const floatx4*)w3f;      // 128 x 16B
            *(floatx4*)(lds + 45056 + tid * 16) = s3[tid];
        }
    }

    // hoisted biases
    const float bb1 = b1[w * 16 + l15];
    const float bb2 = b2[(w & 3) * 16 + l15];
    const float bb3 = b3[l15 < 5 ? l15 : 4];

    const int mi2 = w >> 2;        // GEMM2 row-tile
    const int nt2 = w & 3;         // GEMM2 col-tile

#pragma unroll 1
    for (int t = 0; t < TPT; ++t) {
        // ---- stage: pf -> sA (cvt fp32->fp16, swizzled) ----
#pragma unroll
        for (int jj = 0; jj < 4; ++jj) {
            int c = sc0 + jj * 16;
            half4_t h;
            if (c == 63) {
                h = half4_t{0, 0, 0, 0};            // K-pad cols 252..255
            } else {
                floatx4 f = pf[jj];
                h = half4_t{ (_Float16)f[0], (_Float16)f[1], (_Float16)f[2], (_Float16)f[3] };
            }
            *(half4_t*)(lds + (srow << 9) + ((c * 8) ^ sswz)) = h;
        }
        // ---- issue next tile's loads: in flight across ALL of tile t ----
        if (t + 1 < TPT) ISSUE_A(t + 1)
        lds_barrier();                               // sA ready (vmcnt alive)

        // ---- GEMM1: [32 x 256] @ [256 x 16(cols w*16..)] ----
        floatx4 acc1[2] = { floatx4{0, 0, 0, 0}, floatx4{0, 0, 0, 0} };
#pragma unroll
        for (int ks = 0; ks < 8; ++ks) {
            int cb = ks * 64 + lhi * 16;
#pragma unroll
            for (int mi = 0; mi < 2; ++mi) {
                int r = mi * 16 + l15;
                half8_t a = *(const half8_t*)(lds + (r << 9) + (cb ^ ((r & 7) << 4)));
                acc1[mi] = __builtin_amdgcn_mfma_f32_16x16x32_f16(a, bw1[ks], acc1[mi], 0, 0, 0);
            }
        }

        // ---- h1 = relu(acc1 + b1) -> LDS @16384, col = w*16+l15 ----
        {
            int col2 = (w * 16 + l15) * 2;
#pragma unroll
            for (int mi = 0; mi < 2; ++mi)
#pragma unroll
                for (int ri = 0; ri < 4; ++ri) {
                    int row = mi * 16 + lhi * 4 + ri;
                    float v = acc1[mi][ri] + bb1;
                    v = v > 0.f ? v : 0.f;
                    *(_Float16*)(lds + 16384 + (row << 8) + (col2 ^ ((row & 7) << 4))) = (_Float16)v;
                }
        }
        lds_barrier();                               // h1 ready

        // ---- GEMM2: wave w -> out tile (mi2, nt2), B-frags from LDS ----
        floatx4 acc2 = floatx4{0, 0, 0, 0};
#pragma unroll
        for (int ks = 0; ks < 4; ++ks) {
            int r = mi2 * 16 + l15;
            int cb = ks * 64 + lhi * 16;
            half8_t a  = *(const half8_t*)(lds + 16384 + (r << 8) + (cb ^ ((r & 7) << 4)));
            half8_t bf = *(const half8_t*)(lds + 28672 + ((nt2 * 4 + ks) * 64 + l) * 16);
            acc2 = __builtin_amdgcn_mfma_f32_16x16x32_f16(a, bf, acc2, 0, 0, 0);
        }

        // ---- h2 = relu(acc2 + b2) -> LDS @24576 ----
        {
            int col2 = (nt2 * 16 + l15) * 2;
#pragma unroll
            for (int ri = 0; ri < 4; ++ri) {
                int row = mi2 * 16 + lhi * 4 + ri;
                float v = acc2[ri] + bb2;
                v = v > 0.f ? v : 0.f;
                *(_Float16*)(lds + 24576 + (row << 7) + (col2 ^ ((row & 7) << 4))) = (_Float16)v;
            }
        }
        lds_barrier();                               // h2 ready

        // ---- GEMM3: waves 0,1 -> rows w*16..+15; B from LDS ----
        if (w < 2) {
            floatx4 acc3 = floatx4{0, 0, 0, 0};
#pragma unroll
            for (int ks = 0; ks < 2; ++ks) {
                int r = w * 16 + l15;
                int cb = ks * 64 + lhi * 16;
                half8_t a  = *(const half8_t*)(lds + 24576 + (r << 7) + (cb ^ ((r & 7) << 4)));
                half8_t bf = *(const half8_t*)(lds + 45056 + (ks * 64 + l) * 16);
                acc3 = __builtin_amdgcn_mfma_f32_16x16x32_f16(a, bf, acc3, 0, 0, 0);
            }
            if (l15 < 5) {
#pragma unroll
                for (int ri = 0; ri < 4; ++ri) {
                    int grow = row0 + t * 32 + w * 16 + lhi * 4 + ri;
                    enc[(size_t)l15 * Btot + grow] = fast_tanh(acc3[ri] + bb3);
                }
            }
        }
        // loop-around safety: next stage writes sA, last read at GEMM1(t)
        // (two barriers ago); h1/h2 similarly separated by >=1 barrier.
    }
#undef ISSUE_A
}

// ---------------------------------------------------------------------------
// K2: quantum circuit + back MLP, one thread per batch row.
// ---------------------------------------------------------------------------
template<int P>
__device__ __forceinline__ void ry_g(float* re, float* im, float c, float s) {
    constexpr int STR = 1 << P;
#pragma unroll
    for (int base = 0; base < 32; base += 2 * STR)
#pragma unroll
        for (int d = 0; d < STR; ++d) {
            int i0 = base + d, i1 = i0 + STR;
            float r0 = re[i0], r1 = re[i1], m0 = im[i0], m1 = im[i1];
            re[i0] = c * r0 - s * r1;  re[i1] = s * r0 + c * r1;
            im[i0] = c * m0 - s * m1;  im[i1] = s * m0 + c * m1;
        }
}

template<int P>
__device__ __forceinline__ void rz_g(float* re, float* im, float c, float s) {
#pragma unroll
    for (int i = 0; i < 32; ++i) {
        float t = ((i >> P) & 1) ? s : -s;
        float r = re[i], m = im[i];
        re[i] = c * r - t * m;
        im[i] = c * m + t * r;
    }
}

template<int PC, int PT>
__device__ __forceinline__ void cnot_g(float* re, float* im) {
#pragma unroll
    for (int i = 0; i < 32; ++i) {
        if (((i >> PC) & 1) && !((i >> PT) & 1)) {
            int j = i | (1 << PT);
            float t;
            t = re[i]; re[i] = re[j]; re[j] = t;
            t = im[i]; im[i] = im[j]; im[j] = t;
        }
    }
}

__global__ __launch_bounds__(256) void back_kernel(
    const float* __restrict__ enc, const float* __restrict__ qp,
    const float* __restrict__ D1, const float* __restrict__ d1,
    const float* __restrict__ D2, const float* __restrict__ d2,
    const float* __restrict__ D3, const float* __restrict__ d3,
    float* __restrict__ out, int Btot) {
    __shared__ float sD1[160], sd1[32], sD2[512], sd2[16], sD3[64], sd3[4];
    __shared__ float sQc[30], sQs[30];
    const int tid = threadIdx.x;
    for (int i = tid; i < 512; i += 256) sD2[i] = D2[i];
    if (tid < 160) sD1[tid] = D1[tid];
    if (tid < 32)  sd1[tid] = d1[tid];
    if (tid < 64)  sD3[tid] = D3[tid];
    if (tid < 16)  sd2[tid] = d2[tid];
    if (tid < 4)   sd3[tid] = d3[tid];
    if (tid < 30) { float h = 0.5f * qp[tid]; sQc[tid] = cosf(h); sQs[tid] = sinf(h); }
    __syncthreads();

    const size_t r = (size_t)blockIdx.x * 256 + tid;

    float cq[5], sq[5];
    const float HPI = 1.57079632679489662f;   // pi/2
#pragma unroll
    for (int i = 0; i < 5; ++i) {
        float a = enc[(size_t)i * Btot + r] * HPI;
        cq[i] = __cosf(a);
        sq[i] = __sinf(a);
    }
    float re[32], im[32];
#pragma unroll
    for (int i = 0; i < 32; ++i) {
        float v = ((i >> 4) & 1) ? sq[0] : cq[0];
        v *= ((i >> 3) & 1) ? sq[1] : cq[1];
        v *= ((i >> 2) & 1) ? sq[2] : cq[2];
        v *= ((i >> 1) & 1) ? sq[3] : cq[3];
        v *= ( i       & 1) ? sq[4] : cq[4];
        re[i] = v;
        im[i] = 0.f;
    }

#pragma unroll
    for (int lay = 0; lay < 3; ++lay) {
        const float* c = sQc + lay * 10;
        const float* s = sQs + lay * 10;
        ry_g<4>(re, im, c[0], s[0]);  rz_g<4>(re, im, c[1], s[1]);
        ry_g<3>(re, im, c[2], s[2]);  rz_g<3>(re, im, c[3], s[3]);
        ry_g<2>(re, im, c[4], s[4]);  rz_g<2>(re, im, c[5], s[5]);
        ry_g<1>(re, im, c[6], s[6]);  rz_g<1>(re, im, c[7], s[7]);
        ry_g<0>(re, im, c[8], s[8]);  rz_g<0>(re, im, c[9], s[9]);
        cnot_g<4, 3>(re, im);
        cnot_g<3, 2>(re, im);
        cnot_g<2, 1>(re, im);
        cnot_g<1, 0>(re, im);
    }

    float q[5] = {0, 0, 0, 0, 0};
#pragma unroll
    for (int i = 0; i < 32; ++i) {
        float p = re[i] * re[i] + im[i] * im[i];
        q[0] += ((i >> 4) & 1) ? -p : p;
        q[1] += ((i >> 3) & 1) ? -p : p;
        q[2] += ((i >> 2) & 1) ? -p : p;
        q[3] += ((i >> 1) & 1) ? -p : p;
        q[4] += ( i       & 1) ? -p : p;
    }

    float h1[32];
#pragma unroll
    for (int j = 0; j < 32; ++j) {
        float a = sd1[j];
#pragma unroll
        for (int k = 0; k < 5; ++k) a += q[k] * sD1[k * 32 + j];
        h1[j] = a > 0.f ? a : 0.f;
    }
    float h2[16];
#pragma unroll
    for (int j = 0; j < 16; ++j) {
        float a = sd2[j];
#pragma unroll
        for (int k = 0; k < 32; ++k) a += h1[k] * sD2[k * 16 + j];
        h2[j] = a > 0.f ? a : 0.f;
    }
    floatx4 o;
#pragma unroll
    for (int j = 0; j < 4; ++j) {
        float a = sd3[j];
#pragma unroll
        for (int k = 0; k < 16; ++k) a += h2[k] * sD3[k * 4 + j];
        o[j] = a;
    }
    *(floatx4*)(out + r * 4) = o;
}

// ---------------------------------------------------------------------------
extern "C" void kernel_launch(void* const* d_in, const int* in_sizes, int n_in,
                              void* d_out, int out_size, void* d_ws, size_t ws_size,
                              hipStream_t stream) {
    const float* state = (const float*)d_in[0];
    const float* W1 = (const float*)d_in[1];
    const float* b1 = (const float*)d_in[2];
    const float* W2 = (const float*)d_in[3];
    const float* b2 = (const float*)d_in[4];
    const float* W3 = (const float*)d_in[5];
    const float* b3 = (const float*)d_in[6];
    const float* qp = (const float*)d_in[7];
    const float* D1 = (const float*)d_in[8];
    const float* d1 = (const float*)d_in[9];
    const float* D2 = (const float*)d_in[10];
    const float* d2 = (const float*)d_in[11];
    const float* D3 = (const float*)d_in[12];
    const float* d3 = (const float*)d_in[13];
    float* out = (float*)d_out;

    const int B = in_sizes[0] / 252;     // 131072

    char* ws = (char*)d_ws;
    _Float16* w1f = (_Float16*)ws;                         // 64 KB
    _Float16* w2f = (_Float16*)(ws + 65536);               // 16 KB
    _Float16* w3f = (_Float16*)(ws + 65536 + 16384);       // 2 KB
    float*    enc = (float*)(ws + 65536 + 16384 + 2048);   // SoA [5][B] fp32

    prep_all<<<82, 64, 0, stream>>>(W1, W2, W3, w1f, w2f, w3f);
    front_kernel<<<B / (32 * TPT), 512, 0, stream>>>(state, w1f, b1, w2f, b2, w3f, b3, enc, B);
    back_kernel<<<B / 256, 256, 0, stream>>>(enc, qp, D1, d1, D2, d2, D3, d3, out, B);
}